// Round 2
// baseline (180.693 us; speedup 1.0000x reference)
//
#include <hip/hip_runtime.h>

#define NROW 200000
#define RDIM 32
#define BATCH 131072
#define STEP 0.01f

// ---------------------------------------------------------------------------
// Scatter: one 32-lane group per batch element. lane == r index (R==32).
// accS/accT are the two halves of d_out, pre-zeroed; cnt is in d_ws.
// ---------------------------------------------------------------------------
__global__ __launch_bounds__(256) void em_scatter(
    const float* __restrict__ U0, const float* __restrict__ U1,
    const float* __restrict__ U2, const float* __restrict__ L,
    const float* __restrict__ vals, const int* __restrict__ entries,
    float* __restrict__ accS, float* __restrict__ accT, int* __restrict__ cnt)
{
    int gid  = blockIdx.x * blockDim.x + threadIdx.x;
    int i    = gid >> 5;      // batch element
    int lane = gid & 31;      // r index
    if (i >= BATCH) return;

    int e0 = entries[i * 3 + 0];
    int e1 = entries[i * 3 + 1];
    int e2 = entries[i * 3 + 2];

    float Lr = L[lane];
    float g0 = U0[(size_t)e0 * RDIM + lane];
    float g1 = U1[(size_t)e1 * RDIM + lane];
    float g2 = U2[(size_t)e2 * RDIM + lane];

    float p   = g0 * g1 * g2;
    float Lp  = Lr * p;
    float phi = Lp;
    #pragma unroll
    for (int m = 1; m < 32; m <<= 1) phi += __shfl_xor(phi, m);

    float wi     = 0.5f / phi * tanhf(0.5f * phi);
    float ki     = vals[i] - 0.5f;
    float common = ki - (phi - Lp) * wi;   // ki - d_vec*wi (same for all dims)

    // d = 0: prod_others = g1*g2
    {
        float c = Lr * (g1 * g2);
        size_t off = ((size_t)0 * NROW + e0) * RDIM + lane;
        atomicAdd(&accS[off], c * c * wi);
        atomicAdd(&accT[off], common * c);
    }
    // d = 1: prod_others = g0*g2
    {
        float c = Lr * (g0 * g2);
        size_t off = ((size_t)1 * NROW + e1) * RDIM + lane;
        atomicAdd(&accS[off], c * c * wi);
        atomicAdd(&accT[off], common * c);
    }
    // d = 2: prod_others = g0*g1
    {
        float c = Lr * (g0 * g1);
        size_t off = ((size_t)2 * NROW + e2) * RDIM + lane;
        atomicAdd(&accS[off], c * c * wi);
        atomicAdd(&accT[off], common * c);
    }

    if (lane == 0) {
        atomicAdd(&cnt[0 * NROW + e0], 1);
        atomicAdd(&cnt[1 * NROW + e1], 1);
        atomicAdd(&cnt[2 * NROW + e2], 1);
    }
}

// ---------------------------------------------------------------------------
// Finalize: out[plane][row][r] = touched ? (1-STEP)*in + STEP*acc : in
// planes: 0..2 = S0..S2, 3..5 = T0..T2. float4 per thread.
// ---------------------------------------------------------------------------
__global__ __launch_bounds__(256) void em_finalize(
    const float* __restrict__ S0, const float* __restrict__ S1,
    const float* __restrict__ S2, const float* __restrict__ T0,
    const float* __restrict__ T1, const float* __restrict__ T2,
    const int* __restrict__ cnt, float* __restrict__ out)
{
    const long per_plane = (long)NROW * (RDIM / 4);   // float4 units
    long t = (long)blockIdx.x * blockDim.x + threadIdx.x;
    if (t >= 6 * per_plane) return;

    int  plane  = (int)(t / per_plane);
    long within = t % per_plane;
    int  row    = (int)(within >> 3);
    int  r4     = (int)(within & 7) * 4;

    const float* src = (plane == 0) ? S0 : (plane == 1) ? S1 : (plane == 2) ? S2
                     : (plane == 3) ? T0 : (plane == 4) ? T1 : T2;
    int d = (plane >= 3) ? plane - 3 : plane;

    bool touched = cnt[(size_t)d * NROW + row] > 0;

    size_t src_off = (size_t)row * RDIM + r4;
    size_t out_off = (size_t)plane * NROW * RDIM + src_off;

    float4 in  = *(const float4*)(src + src_off);
    float4 o;
    if (touched) {
        float4 acc = *(const float4*)(out + out_off);
        o.x = (1.0f - STEP) * in.x + STEP * acc.x;
        o.y = (1.0f - STEP) * in.y + STEP * acc.y;
        o.z = (1.0f - STEP) * in.z + STEP * acc.z;
        o.w = (1.0f - STEP) * in.w + STEP * acc.w;
    } else {
        o = in;
    }
    *(float4*)(out + out_off) = o;
}

extern "C" void kernel_launch(void* const* d_in, const int* in_sizes, int n_in,
                              void* d_out, int out_size, void* d_ws, size_t ws_size,
                              hipStream_t stream)
{
    // setup_inputs() dict insertion order (built inside the per-dim loop!):
    // 0:U0 1:S0 2:T0 3:U1 4:S1 5:T1 6:U2 7:S2 8:T2 9:L 10:batch_vals 11:batch_entries
    const float* U0 = (const float*)d_in[0];
    const float* S0 = (const float*)d_in[1];
    const float* T0 = (const float*)d_in[2];
    const float* U1 = (const float*)d_in[3];
    const float* S1 = (const float*)d_in[4];
    const float* T1 = (const float*)d_in[5];
    const float* U2 = (const float*)d_in[6];
    const float* S2 = (const float*)d_in[7];
    const float* T2 = (const float*)d_in[8];
    const float* L  = (const float*)d_in[9];
    const float* bv = (const float*)d_in[10];
    const int*   be = (const int*)d_in[11];

    float* out  = (float*)d_out;
    int*   cnt  = (int*)d_ws;                       // 3*NROW ints = 2.4 MB
    float* accS = out;                              // [3][NROW][32]
    float* accT = out + (size_t)3 * NROW * RDIM;    // [3][NROW][32]

    hipMemsetAsync(d_out, 0, (size_t)out_size * sizeof(float), stream);
    hipMemsetAsync(cnt, 0, (size_t)3 * NROW * sizeof(int), stream);

    int sblocks = (BATCH * 32 + 255) / 256;         // 16384
    em_scatter<<<sblocks, 256, 0, stream>>>(U0, U1, U2, L, bv, be, accS, accT, cnt);

    long fthreads = 6L * NROW * (RDIM / 4);         // 9.6e6
    int  fblocks  = (int)((fthreads + 255) / 256);  // 37500
    em_finalize<<<fblocks, 256, 0, stream>>>(S0, S1, S2, T0, T1, T2, cnt, out);
}

// Round 3
// 168.428 us; speedup vs baseline: 1.0728x; 1.0728x over previous
//
#include <hip/hip_runtime.h>

#define NROW 200000
#define RDIM 32
#define BATCH 131072
#define STEP 0.01f

// ===========================================================================
// FAST PATH: linked-list gather (no fp atomics, no big memset)
// ws layout: head int[3*NROW]  (memset 0xFF -> -1), next int[3*BATCH]
// ===========================================================================

// Build per-(d,row) chains. tid = e*3+d so be[tid] is coalesced.
__global__ __launch_bounds__(256) void em_build(
    const int* __restrict__ be, int* __restrict__ head, int* __restrict__ nxt)
{
    int tid = blockIdx.x * blockDim.x + threadIdx.x;
    if (tid >= BATCH * 3) return;
    int d   = tid % 3;
    int row = be[tid];
    nxt[tid] = atomicExch(&head[d * NROW + row], tid);
}

// One 32-lane group per (d,row): walk chain, accumulate in registers,
// blend and write output row for both S and T planes.
__global__ __launch_bounds__(256) void em_gather(
    const float* __restrict__ U0, const float* __restrict__ U1,
    const float* __restrict__ U2,
    const float* __restrict__ S0, const float* __restrict__ S1,
    const float* __restrict__ S2,
    const float* __restrict__ T0, const float* __restrict__ T1,
    const float* __restrict__ T2,
    const float* __restrict__ L,  const float* __restrict__ bv,
    const int* __restrict__ be,
    const int* __restrict__ head, const int* __restrict__ nxt,
    float* __restrict__ out)
{
    int gid   = blockIdx.x * blockDim.x + threadIdx.x;
    int group = gid >> 5;
    int lane  = gid & 31;
    if (group >= 3 * NROW) return;

    int d   = group / NROW;
    int row = group - d * NROW;

    const float* Ud  = (d == 0) ? U0 : (d == 1) ? U1 : U2;
    const float* Uo1 = (d == 0) ? U1 : U0;     // other dims for d: (1,2),(0,2),(0,1)
    const float* Uo2 = (d == 2) ? U1 : U2;
    int o1 = (d == 0) ? 1 : 0;
    int o2 = (d == 2) ? 1 : 2;
    const float* Ssrc = (d == 0) ? S0 : (d == 1) ? S1 : S2;
    const float* Tsrc = (d == 0) ? T0 : (d == 1) ? T1 : T2;

    size_t row_off = (size_t)row * RDIM + lane;
    float s_in = Ssrc[row_off];
    float t_in = Tsrc[row_off];

    int   t    = head[group];
    float outS = s_in;
    float outT = t_in;

    if (t != -1) {   // uniform across the 32-lane group
        float Lr = L[lane];
        float gd = Ud[row_off];
        float sacc = 0.0f, tacc = 0.0f;
        while (t != -1) {
            int e  = t / 3;
            int r1 = be[e * 3 + o1];
            int r2 = be[e * 3 + o2];
            float g1 = Uo1[(size_t)r1 * RDIM + lane];
            float g2 = Uo2[(size_t)r2 * RDIM + lane];
            float ki = bv[e] - 0.5f;

            float c   = Lr * g1 * g2;   // L * prod_others for dim d
            float Lp  = c * gd;         // L * g0*g1*g2
            float phi = Lp;
            #pragma unroll
            for (int m = 1; m < 32; m <<= 1) phi += __shfl_xor(phi, m);

            float wi = 0.5f / phi * tanhf(0.5f * phi);
            sacc += c * c * wi;
            tacc += (ki - (phi - Lp) * wi) * c;

            t = nxt[t];
        }
        outS = (1.0f - STEP) * s_in + STEP * sacc;
        outT = (1.0f - STEP) * t_in + STEP * tacc;
    }

    size_t offS = ((size_t)d * NROW + row) * RDIM + lane;
    out[offS] = outS;
    out[(size_t)3 * NROW * RDIM + offS] = outT;
}

// ===========================================================================
// FALLBACK PATH (proven Round-2 kernels) — used only if ws_size < 4 MB
// ===========================================================================
__global__ __launch_bounds__(256) void em_scatter(
    const float* __restrict__ U0, const float* __restrict__ U1,
    const float* __restrict__ U2, const float* __restrict__ L,
    const float* __restrict__ vals, const int* __restrict__ entries,
    float* __restrict__ accS, float* __restrict__ accT, int* __restrict__ cnt)
{
    int gid  = blockIdx.x * blockDim.x + threadIdx.x;
    int i    = gid >> 5;
    int lane = gid & 31;
    if (i >= BATCH) return;

    int e0 = entries[i * 3 + 0];
    int e1 = entries[i * 3 + 1];
    int e2 = entries[i * 3 + 2];

    float Lr = L[lane];
    float g0 = U0[(size_t)e0 * RDIM + lane];
    float g1 = U1[(size_t)e1 * RDIM + lane];
    float g2 = U2[(size_t)e2 * RDIM + lane];

    float p   = g0 * g1 * g2;
    float Lp  = Lr * p;
    float phi = Lp;
    #pragma unroll
    for (int m = 1; m < 32; m <<= 1) phi += __shfl_xor(phi, m);

    float wi     = 0.5f / phi * tanhf(0.5f * phi);
    float ki     = vals[i] - 0.5f;
    float common = ki - (phi - Lp) * wi;

    {
        float c = Lr * (g1 * g2);
        size_t off = ((size_t)0 * NROW + e0) * RDIM + lane;
        atomicAdd(&accS[off], c * c * wi);
        atomicAdd(&accT[off], common * c);
    }
    {
        float c = Lr * (g0 * g2);
        size_t off = ((size_t)1 * NROW + e1) * RDIM + lane;
        atomicAdd(&accS[off], c * c * wi);
        atomicAdd(&accT[off], common * c);
    }
    {
        float c = Lr * (g0 * g1);
        size_t off = ((size_t)2 * NROW + e2) * RDIM + lane;
        atomicAdd(&accS[off], c * c * wi);
        atomicAdd(&accT[off], common * c);
    }

    if (lane == 0) {
        atomicAdd(&cnt[0 * NROW + e0], 1);
        atomicAdd(&cnt[1 * NROW + e1], 1);
        atomicAdd(&cnt[2 * NROW + e2], 1);
    }
}

__global__ __launch_bounds__(256) void em_finalize(
    const float* __restrict__ S0, const float* __restrict__ S1,
    const float* __restrict__ S2, const float* __restrict__ T0,
    const float* __restrict__ T1, const float* __restrict__ T2,
    const int* __restrict__ cnt, float* __restrict__ out)
{
    const long per_plane = (long)NROW * (RDIM / 4);
    long t = (long)blockIdx.x * blockDim.x + threadIdx.x;
    if (t >= 6 * per_plane) return;

    int  plane  = (int)(t / per_plane);
    long within = t % per_plane;
    int  row    = (int)(within >> 3);
    int  r4     = (int)(within & 7) * 4;

    const float* src = (plane == 0) ? S0 : (plane == 1) ? S1 : (plane == 2) ? S2
                     : (plane == 3) ? T0 : (plane == 4) ? T1 : T2;
    int d = (plane >= 3) ? plane - 3 : plane;

    bool touched = cnt[(size_t)d * NROW + row] > 0;

    size_t src_off = (size_t)row * RDIM + r4;
    size_t out_off = (size_t)plane * NROW * RDIM + src_off;

    float4 in = *(const float4*)(src + src_off);
    float4 o;
    if (touched) {
        float4 acc = *(const float4*)(out + out_off);
        o.x = (1.0f - STEP) * in.x + STEP * acc.x;
        o.y = (1.0f - STEP) * in.y + STEP * acc.y;
        o.z = (1.0f - STEP) * in.z + STEP * acc.z;
        o.w = (1.0f - STEP) * in.w + STEP * acc.w;
    } else {
        o = in;
    }
    *(float4*)(out + out_off) = o;
}

// ===========================================================================
extern "C" void kernel_launch(void* const* d_in, const int* in_sizes, int n_in,
                              void* d_out, int out_size, void* d_ws, size_t ws_size,
                              hipStream_t stream)
{
    // setup_inputs() insertion order: U0,S0,T0, U1,S1,T1, U2,S2,T2, L, bv, be
    const float* U0 = (const float*)d_in[0];
    const float* S0 = (const float*)d_in[1];
    const float* T0 = (const float*)d_in[2];
    const float* U1 = (const float*)d_in[3];
    const float* S1 = (const float*)d_in[4];
    const float* T1 = (const float*)d_in[5];
    const float* U2 = (const float*)d_in[6];
    const float* S2 = (const float*)d_in[7];
    const float* T2 = (const float*)d_in[8];
    const float* L  = (const float*)d_in[9];
    const float* bv = (const float*)d_in[10];
    const int*   be = (const int*)d_in[11];

    float* out = (float*)d_out;

    const size_t ws_needed = ((size_t)3 * NROW + (size_t)3 * BATCH) * sizeof(int);

    if (ws_size >= ws_needed) {
        // ---- fast path: linked-list gather ----
        int* head_ = (int*)d_ws;            // [3*NROW]
        int* nxt   = head_ + 3 * NROW;      // [3*BATCH]

        hipMemsetAsync(head_, 0xFF, (size_t)3 * NROW * sizeof(int), stream); // -1

        int bblocks = (BATCH * 3 + 255) / 256;   // 1536
        em_build<<<bblocks, 256, 0, stream>>>(be, head_, nxt);

        long gthreads = 3L * NROW * 32;          // 19.2M
        int  gblocks  = (int)((gthreads + 255) / 256);  // 75000
        em_gather<<<gblocks, 256, 0, stream>>>(U0, U1, U2, S0, S1, S2,
                                               T0, T1, T2, L, bv, be,
                                               head_, nxt, out);
    } else {
        // ---- fallback: round-2 scatter + finalize ----
        int*   cnt  = (int*)d_ws;
        float* accS = out;
        float* accT = out + (size_t)3 * NROW * RDIM;

        hipMemsetAsync(d_out, 0, (size_t)out_size * sizeof(float), stream);
        hipMemsetAsync(cnt, 0, (size_t)3 * NROW * sizeof(int), stream);

        int sblocks = (BATCH * 32 + 255) / 256;
        em_scatter<<<sblocks, 256, 0, stream>>>(U0, U1, U2, L, bv, be, accS, accT, cnt);

        long fthreads = 6L * NROW * (RDIM / 4);
        int  fblocks  = (int)((fthreads + 255) / 256);
        em_finalize<<<fblocks, 256, 0, stream>>>(S0, S1, S2, T0, T1, T2, cnt, out);
    }
}

// Round 4
// 152.342 us; speedup vs baseline: 1.1861x; 1.1056x over previous
//
#include <hip/hip_runtime.h>
#include <hip/hip_runtime.h>

#define NROW 200000
#define RDIM 32
#define BATCH 131072
#define STEP 0.01f

// ===========================================================================
// ws layout (fast path), all 8B-aligned:
//   head  int[3*NROW]        (memset 0xFF -> -1)
//   nxt   int[3*BATCH]
//   scal  float2[BATCH]      (A = ki - phi*wi, wi)
//   Lp    float[BATCH*32]    (L_r * g0*g1*g2 per lane)
// ===========================================================================

// Build per-(d,row) chains. tid = e*3+d so be[tid] is coalesced.
__global__ __launch_bounds__(256) void em_build(
    const int* __restrict__ be, int* __restrict__ head, int* __restrict__ nxt)
{
    int tid = blockIdx.x * blockDim.x + threadIdx.x;
    if (tid >= BATCH * 3) return;
    int d   = tid % 3;
    int row = be[tid];
    nxt[tid] = atomicExch(&head[d * NROW + row], tid);
}

// Per batch element: gather 3 U rows once; compute Lp vector, phi, wi, A.
__global__ __launch_bounds__(256) void em_precompute(
    const float* __restrict__ U0, const float* __restrict__ U1,
    const float* __restrict__ U2, const float* __restrict__ L,
    const float* __restrict__ bv, const int* __restrict__ be,
    float2* __restrict__ scal, float* __restrict__ LpBuf)
{
    int gid  = blockIdx.x * blockDim.x + threadIdx.x;
    int i    = gid >> 5;      // batch element
    int lane = gid & 31;      // r index
    if (i >= BATCH) return;

    int e0 = be[i * 3 + 0];
    int e1 = be[i * 3 + 1];
    int e2 = be[i * 3 + 2];

    float g0 = U0[(size_t)e0 * RDIM + lane];
    float g1 = U1[(size_t)e1 * RDIM + lane];
    float g2 = U2[(size_t)e2 * RDIM + lane];

    float Lp  = L[lane] * g0 * g1 * g2;
    float phi = Lp;
    #pragma unroll
    for (int m = 1; m < 32; m <<= 1) phi += __shfl_xor(phi, m);

    float wi = 0.5f / phi * tanhf(0.5f * phi);

    LpBuf[(size_t)i * RDIM + lane] = Lp;
    if (lane == 0) {
        float A = (bv[i] - 0.5f) - phi * wi;
        scal[i] = make_float2(A, wi);
    }
}

// Per (d,row): walk chain with cheap per-step work; blend + write S,T rows.
__global__ __launch_bounds__(256) void em_apply(
    const float* __restrict__ U0, const float* __restrict__ U1,
    const float* __restrict__ U2,
    const float* __restrict__ S0, const float* __restrict__ S1,
    const float* __restrict__ S2,
    const float* __restrict__ T0, const float* __restrict__ T1,
    const float* __restrict__ T2,
    const int* __restrict__ head, const int* __restrict__ nxt,
    const float2* __restrict__ scal, const float* __restrict__ LpBuf,
    float* __restrict__ out)
{
    int gid   = blockIdx.x * blockDim.x + threadIdx.x;
    int group = gid >> 5;
    int lane  = gid & 31;
    if (group >= 3 * NROW) return;

    int d   = group / NROW;
    int row = group - d * NROW;

    const float* Ud   = (d == 0) ? U0 : (d == 1) ? U1 : U2;
    const float* Ssrc = (d == 0) ? S0 : (d == 1) ? S1 : S2;
    const float* Tsrc = (d == 0) ? T0 : (d == 1) ? T1 : T2;

    size_t row_off = (size_t)row * RDIM + lane;
    float s_in = Ssrc[row_off];
    float t_in = Tsrc[row_off];

    int   t    = head[group];
    float outS = s_in;
    float outT = t_in;

    if (t != -1) {   // uniform across the 32-lane group
        float gd  = Ud[row_off];
        float rgd = __builtin_amdgcn_rcpf(gd);   // gd in [0.05,1] — safe
        float sacc = 0.0f, tacc = 0.0f;
        while (t != -1) {
            int e = t / 3;
            float2 aw = scal[e];                          // broadcast 8B
            float  Lp = LpBuf[(size_t)e * RDIM + lane];   // coalesced 128B
            float  c  = Lp * rgd;
            sacc += aw.y * c * c;
            tacc += (aw.x + aw.y * Lp) * c;
            t = nxt[t];
        }
        outS = (1.0f - STEP) * s_in + STEP * sacc;
        outT = (1.0f - STEP) * t_in + STEP * tacc;
    }

    size_t offS = ((size_t)d * NROW + row) * RDIM + lane;
    out[offS] = outS;
    out[(size_t)3 * NROW * RDIM + offS] = outT;
}

// ===========================================================================
// FALLBACK PATH (proven Round-3 kernel) — used only if ws too small
// ===========================================================================
__global__ __launch_bounds__(256) void em_gather(
    const float* __restrict__ U0, const float* __restrict__ U1,
    const float* __restrict__ U2,
    const float* __restrict__ S0, const float* __restrict__ S1,
    const float* __restrict__ S2,
    const float* __restrict__ T0, const float* __restrict__ T1,
    const float* __restrict__ T2,
    const float* __restrict__ L,  const float* __restrict__ bv,
    const int* __restrict__ be,
    const int* __restrict__ head, const int* __restrict__ nxt,
    float* __restrict__ out)
{
    int gid   = blockIdx.x * blockDim.x + threadIdx.x;
    int group = gid >> 5;
    int lane  = gid & 31;
    if (group >= 3 * NROW) return;

    int d   = group / NROW;
    int row = group - d * NROW;

    const float* Ud  = (d == 0) ? U0 : (d == 1) ? U1 : U2;
    const float* Uo1 = (d == 0) ? U1 : U0;
    const float* Uo2 = (d == 2) ? U1 : U2;
    int o1 = (d == 0) ? 1 : 0;
    int o2 = (d == 2) ? 1 : 2;
    const float* Ssrc = (d == 0) ? S0 : (d == 1) ? S1 : S2;
    const float* Tsrc = (d == 0) ? T0 : (d == 1) ? T1 : T2;

    size_t row_off = (size_t)row * RDIM + lane;
    float s_in = Ssrc[row_off];
    float t_in = Tsrc[row_off];

    int   t    = head[group];
    float outS = s_in;
    float outT = t_in;

    if (t != -1) {
        float Lr = L[lane];
        float gd = Ud[row_off];
        float sacc = 0.0f, tacc = 0.0f;
        while (t != -1) {
            int e  = t / 3;
            int r1 = be[e * 3 + o1];
            int r2 = be[e * 3 + o2];
            float g1 = Uo1[(size_t)r1 * RDIM + lane];
            float g2 = Uo2[(size_t)r2 * RDIM + lane];
            float ki = bv[e] - 0.5f;

            float c   = Lr * g1 * g2;
            float Lp  = c * gd;
            float phi = Lp;
            #pragma unroll
            for (int m = 1; m < 32; m <<= 1) phi += __shfl_xor(phi, m);

            float wi = 0.5f / phi * tanhf(0.5f * phi);
            sacc += c * c * wi;
            tacc += (ki - (phi - Lp) * wi) * c;

            t = nxt[t];
        }
        outS = (1.0f - STEP) * s_in + STEP * sacc;
        outT = (1.0f - STEP) * t_in + STEP * tacc;
    }

    size_t offS = ((size_t)d * NROW + row) * RDIM + lane;
    out[offS] = outS;
    out[(size_t)3 * NROW * RDIM + offS] = outT;
}

// ===========================================================================
extern "C" void kernel_launch(void* const* d_in, const int* in_sizes, int n_in,
                              void* d_out, int out_size, void* d_ws, size_t ws_size,
                              hipStream_t stream)
{
    // setup_inputs() insertion order: U0,S0,T0, U1,S1,T1, U2,S2,T2, L, bv, be
    const float* U0 = (const float*)d_in[0];
    const float* S0 = (const float*)d_in[1];
    const float* T0 = (const float*)d_in[2];
    const float* U1 = (const float*)d_in[3];
    const float* S1 = (const float*)d_in[4];
    const float* T1 = (const float*)d_in[5];
    const float* U2 = (const float*)d_in[6];
    const float* S2 = (const float*)d_in[7];
    const float* T2 = (const float*)d_in[8];
    const float* L  = (const float*)d_in[9];
    const float* bv = (const float*)d_in[10];
    const int*   be = (const int*)d_in[11];

    float* out = (float*)d_out;

    const size_t head_n = (size_t)3 * NROW;    // ints
    const size_t nxt_n  = (size_t)3 * BATCH;   // ints
    const size_t ws_list = (head_n + nxt_n) * sizeof(int);                 // 3.97 MB
    const size_t ws_fast = ws_list + (size_t)BATCH * sizeof(float2)
                         + (size_t)BATCH * RDIM * sizeof(float);           // ~21.8 MB

    int* head_ = (int*)d_ws;
    int* nxt   = head_ + head_n;

    if (ws_size >= ws_fast) {
        // ---- fast path: precompute + light chain walk ----
        float2* scal  = (float2*)(nxt + nxt_n);
        float*  LpBuf = (float*)(scal + BATCH);

        hipMemsetAsync(head_, 0xFF, head_n * sizeof(int), stream);

        int bblocks = (BATCH * 3 + 255) / 256;
        em_build<<<bblocks, 256, 0, stream>>>(be, head_, nxt);

        int pblocks = (BATCH * 32 + 255) / 256;   // 16384
        em_precompute<<<pblocks, 256, 0, stream>>>(U0, U1, U2, L, bv, be, scal, LpBuf);

        long gthreads = 3L * NROW * 32;
        int  gblocks  = (int)((gthreads + 255) / 256);  // 75000
        em_apply<<<gblocks, 256, 0, stream>>>(U0, U1, U2, S0, S1, S2,
                                              T0, T1, T2, head_, nxt,
                                              scal, LpBuf, out);
    } else {
        // ---- fallback: round-3 linked-list gather ----
        hipMemsetAsync(head_, 0xFF, head_n * sizeof(int), stream);

        int bblocks = (BATCH * 3 + 255) / 256;
        em_build<<<bblocks, 256, 0, stream>>>(be, head_, nxt);

        long gthreads = 3L * NROW * 32;
        int  gblocks  = (int)((gthreads + 255) / 256);
        em_gather<<<gblocks, 256, 0, stream>>>(U0, U1, U2, S0, S1, S2,
                                               T0, T1, T2, L, bv, be,
                                               head_, nxt, out);
    }
}

// Round 5
// 107.833 us; speedup vs baseline: 1.6757x; 1.4128x over previous
//
#include <hip/hip_runtime.h>

#define NROW 200000
#define RDIM 32
#define BATCH 131072
#define STEP 0.01f

// ===========================================================================
// ws layout (fast path), all 8B-aligned:
//   head  int[3*NROW]        (memset 0xFF -> -1)
//   nxt   int[3*BATCH]
//   scal  float2[BATCH]      (A = ki - phi*wi, wi)
//   Lp    float[BATCH*32]    (L_r * g0*g1*g2 per lane)
// ===========================================================================

// Merged precompute + chain build. 8 lanes per batch element, float4 I/O.
// Per element: gather 3 U rows, Lp = L*g0*g1*g2, phi = sum(Lp), wi, A;
// lanes 0..2 of each subgroup also push (e,d) onto the per-(d,row) chain.
__global__ __launch_bounds__(256) void em_pre(
    const float* __restrict__ U0, const float* __restrict__ U1,
    const float* __restrict__ U2, const float* __restrict__ L,
    const float* __restrict__ bv, const int* __restrict__ be,
    int* __restrict__ head, int* __restrict__ nxt,
    float2* __restrict__ scal, float* __restrict__ LpBuf)
{
    int tid = blockIdx.x * blockDim.x + threadIdx.x;
    int i   = tid >> 3;          // batch element
    int sub = tid & 7;           // 4-float slot
    if (i >= BATCH) return;

    int e0 = be[i * 3 + 0];
    int e1 = be[i * 3 + 1];
    int e2 = be[i * 3 + 2];

    float4 g0 = *(const float4*)(U0 + (size_t)e0 * RDIM + sub * 4);
    float4 g1 = *(const float4*)(U1 + (size_t)e1 * RDIM + sub * 4);
    float4 g2 = *(const float4*)(U2 + (size_t)e2 * RDIM + sub * 4);
    float4 Lv = *(const float4*)(L + sub * 4);

    float4 Lp;
    Lp.x = Lv.x * g0.x * g1.x * g2.x;
    Lp.y = Lv.y * g0.y * g1.y * g2.y;
    Lp.z = Lv.z * g0.z * g1.z * g2.z;
    Lp.w = Lv.w * g0.w * g1.w * g2.w;

    float phi = (Lp.x + Lp.y) + (Lp.z + Lp.w);
    phi += __shfl_xor(phi, 1);
    phi += __shfl_xor(phi, 2);
    phi += __shfl_xor(phi, 4);

    float wi = 0.5f / phi * tanhf(0.5f * phi);

    *(float4*)(LpBuf + (size_t)i * RDIM + sub * 4) = Lp;

    if (sub == 0) {
        float A = (bv[i] - 0.5f) - phi * wi;
        scal[i] = make_float2(A, wi);
    }
    if (sub < 3) {
        int row = (sub == 0) ? e0 : (sub == 1) ? e1 : e2;
        int idx = i * 3 + sub;
        nxt[idx] = atomicExch(&head[sub * NROW + row], idx);
    }
}

// 8 lanes per (d,row). float4 everywhere. Walk chain, blend, write S,T rows.
__global__ __launch_bounds__(256) void em_apply_vec(
    const float* __restrict__ U0, const float* __restrict__ U1,
    const float* __restrict__ U2,
    const float* __restrict__ S0, const float* __restrict__ S1,
    const float* __restrict__ S2,
    const float* __restrict__ T0, const float* __restrict__ T1,
    const float* __restrict__ T2,
    const int* __restrict__ head, const int* __restrict__ nxt,
    const float2* __restrict__ scal, const float* __restrict__ LpBuf,
    float* __restrict__ out)
{
    int tid = blockIdx.x * blockDim.x + threadIdx.x;
    int rid = tid >> 3;          // global row id in [0, 3*NROW)
    int sub = tid & 7;
    if (rid >= 3 * NROW) return;

    int d   = rid / NROW;        // uniform per block (NROW % 32 == 0)
    int row = rid - d * NROW;

    const float* Ud   = (d == 0) ? U0 : (d == 1) ? U1 : U2;
    const float* Ssrc = (d == 0) ? S0 : (d == 1) ? S1 : S2;
    const float* Tsrc = (d == 0) ? T0 : (d == 1) ? T1 : T2;

    size_t roff = (size_t)row * RDIM + sub * 4;
    float4 s_in = *(const float4*)(Ssrc + roff);
    float4 t_in = *(const float4*)(Tsrc + roff);

    int    t    = head[rid];
    float4 oS   = s_in;
    float4 oT   = t_in;

    if (t != -1) {   // uniform across the 8-lane subgroup
        float4 gd = *(const float4*)(Ud + roff);
        float4 rg;
        rg.x = __builtin_amdgcn_rcpf(gd.x);   // gd in [0.05,1] — safe
        rg.y = __builtin_amdgcn_rcpf(gd.y);
        rg.z = __builtin_amdgcn_rcpf(gd.z);
        rg.w = __builtin_amdgcn_rcpf(gd.w);

        float4 sa = make_float4(0.f, 0.f, 0.f, 0.f);
        float4 ta = make_float4(0.f, 0.f, 0.f, 0.f);
        while (t != -1) {
            int e = t / 3;
            float2 aw = scal[e];                                       // 8B bcast
            float4 Lp = *(const float4*)(LpBuf + (size_t)e * RDIM + sub * 4);
            float cx = Lp.x * rg.x, cy = Lp.y * rg.y,
                  cz = Lp.z * rg.z, cw = Lp.w * rg.w;
            sa.x += aw.y * cx * cx;  sa.y += aw.y * cy * cy;
            sa.z += aw.y * cz * cz;  sa.w += aw.y * cw * cw;
            ta.x += (aw.x + aw.y * Lp.x) * cx;
            ta.y += (aw.x + aw.y * Lp.y) * cy;
            ta.z += (aw.x + aw.y * Lp.z) * cz;
            ta.w += (aw.x + aw.y * Lp.w) * cw;
            t = nxt[t];
        }
        oS.x = (1.0f - STEP) * s_in.x + STEP * sa.x;
        oS.y = (1.0f - STEP) * s_in.y + STEP * sa.y;
        oS.z = (1.0f - STEP) * s_in.z + STEP * sa.z;
        oS.w = (1.0f - STEP) * s_in.w + STEP * sa.w;
        oT.x = (1.0f - STEP) * t_in.x + STEP * ta.x;
        oT.y = (1.0f - STEP) * t_in.y + STEP * ta.y;
        oT.z = (1.0f - STEP) * t_in.z + STEP * ta.z;
        oT.w = (1.0f - STEP) * t_in.w + STEP * ta.w;
    }

    size_t offS = ((size_t)d * NROW + row) * RDIM + sub * 4;
    *(float4*)(out + offS) = oS;
    *(float4*)(out + (size_t)3 * NROW * RDIM + offS) = oT;
}

// ===========================================================================
// FALLBACK PATH (proven Round-3 kernels) — used only if ws too small
// ===========================================================================
__global__ __launch_bounds__(256) void em_build(
    const int* __restrict__ be, int* __restrict__ head, int* __restrict__ nxt)
{
    int tid = blockIdx.x * blockDim.x + threadIdx.x;
    if (tid >= BATCH * 3) return;
    int d   = tid % 3;
    int row = be[tid];
    nxt[tid] = atomicExch(&head[d * NROW + row], tid);
}

__global__ __launch_bounds__(256) void em_gather(
    const float* __restrict__ U0, const float* __restrict__ U1,
    const float* __restrict__ U2,
    const float* __restrict__ S0, const float* __restrict__ S1,
    const float* __restrict__ S2,
    const float* __restrict__ T0, const float* __restrict__ T1,
    const float* __restrict__ T2,
    const float* __restrict__ L,  const float* __restrict__ bv,
    const int* __restrict__ be,
    const int* __restrict__ head, const int* __restrict__ nxt,
    float* __restrict__ out)
{
    int gid   = blockIdx.x * blockDim.x + threadIdx.x;
    int group = gid >> 5;
    int lane  = gid & 31;
    if (group >= 3 * NROW) return;

    int d   = group / NROW;
    int row = group - d * NROW;

    const float* Ud  = (d == 0) ? U0 : (d == 1) ? U1 : U2;
    const float* Uo1 = (d == 0) ? U1 : U0;
    const float* Uo2 = (d == 2) ? U1 : U2;
    int o1 = (d == 0) ? 1 : 0;
    int o2 = (d == 2) ? 1 : 2;
    const float* Ssrc = (d == 0) ? S0 : (d == 1) ? S1 : S2;
    const float* Tsrc = (d == 0) ? T0 : (d == 1) ? T1 : T2;

    size_t row_off = (size_t)row * RDIM + lane;
    float s_in = Ssrc[row_off];
    float t_in = Tsrc[row_off];

    int   t    = head[group];
    float outS = s_in;
    float outT = t_in;

    if (t != -1) {
        float Lr = L[lane];
        float gd = Ud[row_off];
        float sacc = 0.0f, tacc = 0.0f;
        while (t != -1) {
            int e  = t / 3;
            int r1 = be[e * 3 + o1];
            int r2 = be[e * 3 + o2];
            float g1 = Uo1[(size_t)r1 * RDIM + lane];
            float g2 = Uo2[(size_t)r2 * RDIM + lane];
            float ki = bv[e] - 0.5f;

            float c   = Lr * g1 * g2;
            float Lp  = c * gd;
            float phi = Lp;
            #pragma unroll
            for (int m = 1; m < 32; m <<= 1) phi += __shfl_xor(phi, m);

            float wi = 0.5f / phi * tanhf(0.5f * phi);
            sacc += c * c * wi;
            tacc += (ki - (phi - Lp) * wi) * c;

            t = nxt[t];
        }
        outS = (1.0f - STEP) * s_in + STEP * sacc;
        outT = (1.0f - STEP) * t_in + STEP * tacc;
    }

    size_t offS = ((size_t)d * NROW + row) * RDIM + lane;
    out[offS] = outS;
    out[(size_t)3 * NROW * RDIM + offS] = outT;
}

// ===========================================================================
extern "C" void kernel_launch(void* const* d_in, const int* in_sizes, int n_in,
                              void* d_out, int out_size, void* d_ws, size_t ws_size,
                              hipStream_t stream)
{
    // setup_inputs() insertion order: U0,S0,T0, U1,S1,T1, U2,S2,T2, L, bv, be
    const float* U0 = (const float*)d_in[0];
    const float* S0 = (const float*)d_in[1];
    const float* T0 = (const float*)d_in[2];
    const float* U1 = (const float*)d_in[3];
    const float* S1 = (const float*)d_in[4];
    const float* T1 = (const float*)d_in[5];
    const float* U2 = (const float*)d_in[6];
    const float* S2 = (const float*)d_in[7];
    const float* T2 = (const float*)d_in[8];
    const float* L  = (const float*)d_in[9];
    const float* bv = (const float*)d_in[10];
    const int*   be = (const int*)d_in[11];

    float* out = (float*)d_out;

    const size_t head_n = (size_t)3 * NROW;    // ints
    const size_t nxt_n  = (size_t)3 * BATCH;   // ints
    const size_t ws_fast = (head_n + nxt_n) * sizeof(int)
                         + (size_t)BATCH * sizeof(float2)
                         + (size_t)BATCH * RDIM * sizeof(float);   // ~21.8 MB

    int* head_ = (int*)d_ws;
    int* nxt   = head_ + head_n;

    hipMemsetAsync(head_, 0xFF, head_n * sizeof(int), stream);

    if (ws_size >= ws_fast) {
        // ---- fast path: merged precompute+build, then vectorized apply ----
        float2* scal  = (float2*)(nxt + nxt_n);
        float*  LpBuf = (float*)(scal + BATCH);

        int pblocks = (BATCH * 8 + 255) / 256;    // 4096
        em_pre<<<pblocks, 256, 0, stream>>>(U0, U1, U2, L, bv, be,
                                            head_, nxt, scal, LpBuf);

        long athreads = 3L * NROW * 8;            // 4.8M
        int  ablocks  = (int)((athreads + 255) / 256);  // 18750
        em_apply_vec<<<ablocks, 256, 0, stream>>>(U0, U1, U2, S0, S1, S2,
                                                  T0, T1, T2, head_, nxt,
                                                  scal, LpBuf, out);
    } else {
        // ---- fallback: round-3 linked-list gather ----
        int bblocks = (BATCH * 3 + 255) / 256;
        em_build<<<bblocks, 256, 0, stream>>>(be, head_, nxt);

        long gthreads = 3L * NROW * 32;
        int  gblocks  = (int)((gthreads + 255) / 256);
        em_gather<<<gblocks, 256, 0, stream>>>(U0, U1, U2, S0, S1, S2,
                                               T0, T1, T2, L, bv, be,
                                               head_, nxt, out);
    }
}